// Round 4
// baseline (693.535 us; speedup 1.0000x reference)
//
#include <hip/hip_runtime.h>

#define B_ 8
#define L_ 512
#define K_ 30
#define NIN_ 384
#define HES 11520          // floats per site in h_E
#define BUFW 136           // buf1 row stride (ushort)
#define GFW 96             // geoF row stride (ushort)
// f32 indices inside the per-BLOCK arena:
#define R0_OFF 0
#define T0_OFF 9
#define PL0_OFF 12
#define NPG_OFF 40         // Npg[30][24] -> 40..759
#define PLF_OFF 760        // Pl[30][24] -> 760..1479 (dies before geoF)
#define NM0_OFF 2200       // wave0 nm partial
#define NM1_OFF 2328       // wave1 nm partial
#define LNP_OFF 2456       // 8 floats LN cross-wave partials
#define HARR_OFF 0         // tail: h[128] overlays dead buf1
#define GARR_OFF 128       // tail: g[512] overlays dead buf1
// ushort index:
#define GEOF_OFF 1520      // byte 3040, overlays dead PlFull

// ws fragment-ordered weights (ushort, bf16):
#define W1F_OFF 0
#define W2F_OFF 77824
#define W3F_OFF 94208
#define WIF_OFF 110592
#define WOF_OFF 176128
#define WPF_OFF 241664

typedef __attribute__((ext_vector_type(8))) short short8;
typedef __attribute__((ext_vector_type(8))) unsigned short ushort8;
typedef __attribute__((ext_vector_type(4))) float floatx4;
typedef __attribute__((ext_vector_type(4))) float f32x4;
typedef __attribute__((ext_vector_type(4))) unsigned int uint4v;

__device__ __forceinline__ float b2f(unsigned short u) {
    union { unsigned int i; float f; } x; x.i = ((unsigned int)u) << 16; return x.f;
}
__device__ __forceinline__ unsigned short f2b(float f) {
    unsigned int u = __builtin_bit_cast(unsigned int, f);
    return (unsigned short)((u + 0x7fffu + ((u >> 16) & 1u)) >> 16);
}
__device__ __forceinline__ float gelu_f(float x) {
    return 0.5f * x * (1.0f + erff(x * 0.70710678118654752440f));
}
// f32x8 -> bf16x8 via 4x v_cvt_pk_bf16_f32 (RNE)
__device__ __forceinline__ short8 pack8(const float* p) {
    f32x4 lo = *(const f32x4*)p;
    f32x4 hi = *(const f32x4*)(p + 4);
    unsigned int d0, d1, d2, d3;
    asm("v_cvt_pk_bf16_f32 %0, %1, %2" : "=v"(d0) : "v"(lo[0]), "v"(lo[1]));
    asm("v_cvt_pk_bf16_f32 %0, %1, %2" : "=v"(d1) : "v"(lo[2]), "v"(lo[3]));
    asm("v_cvt_pk_bf16_f32 %0, %1, %2" : "=v"(d2) : "v"(hi[0]), "v"(hi[1]));
    asm("v_cvt_pk_bf16_f32 %0, %1, %2" : "=v"(d3) : "v"(hi[2]), "v"(hi[3]));
    uint4v d = {d0, d1, d2, d3};
    return __builtin_bit_cast(short8, d);
}
__device__ __forceinline__ float dot8(const float* hp, ushort8 v) {
    return hp[0] * b2f(v[0]) + hp[1] * b2f(v[1]) + hp[2] * b2f(v[2]) + hp[3] * b2f(v[3]) +
           hp[4] * b2f(v[4]) + hp[5] * b2f(v[5]) + hp[6] * b2f(v[6]) + hp[7] * b2f(v[7]);
}

// One element per thread; grid covers 245760 exactly. (unchanged)
__global__ __launch_bounds__(256) void prep_kernel(
        const float* __restrict__ W1, const float* __restrict__ W2,
        const float* __restrict__ W3, const float* __restrict__ Wi,
        const float* __restrict__ Wo, const float* __restrict__ Wp,
        unsigned short* __restrict__ ws) {
    int idx = blockIdx.x * 256 + threadIdx.x;
    if (idx < 94208 || (idx >= 241664 && idx < 245760)) {
        const float* in; int i, KC, Kreal, Nreal, Nld;
        if (idx < 77824)      { in = W1; i = idx;          KC = 19; Kreal = 584; Nreal = 128; Nld = 128; }
        else if (idx < 94208) { in = W2; i = idx - 77824;  KC = 4;  Kreal = 128; Nreal = 128; Nld = 128; }
        else                  { in = Wp; i = idx - 241664; KC = 4;  Kreal = 128; Nreal = 24;  Nld = 24;  }
        int f = i >> 9, r = i & 511;
        int ct = f / KC, kc = f % KC;
        int lane = r >> 3, j = r & 7;
        int q = lane >> 4, l = lane & 15;
        int k = kc * 32 + q * 8 + j, n = ct * 16 + l;
        ws[idx] = (k < Kreal && n < Nreal) ? f2b(in[k * Nld + n]) : (unsigned short)0;
    } else if (idx < 110592) {
        int i = idx - 94208;
        int f = i >> 9, r = i & 511;
        int ct = f >> 2, kc = f & 3;
        int lane = r >> 3, j = r & 7;
        int q = lane >> 4, l = lane & 15;
        ws[idx] = f2b(W3[(kc * 32 + q * 8 + j) * 128 + ct * 16 + l]);
    } else if (idx < 176128) {
        int i = idx - 110592;
        int c8 = i >> 12, r = i & 4095;
        int o = r >> 3, ii = r & 7;
        ws[idx] = f2b(Wi[(c8 * 8 + ii) * 512 + o]);
    } else if (idx < 241664) {
        int i = idx - 176128;
        int o8 = i >> 10, r = i & 1023;
        int c = r >> 3, ii = r & 7;
        ws[idx] = f2b(Wo[(o8 * 8 + ii) * 128 + c]);
    }
}

// ONE SITE PER BLOCK, 2 cooperating waves, row-split stages.
// 2-pass ct loops (acc[4] live) so the TRUE live set fits the 64-VGPR
// budget that launch_bounds(128,4) imposes (empirical: budget = 256/arg).
// 64 VGPR + 10240 B LDS -> 8 waves/SIMD, 16 blocks/CU, 32 waves/CU.
__global__ __launch_bounds__(128, 4) void main_kernel(
    const float* __restrict__ h_V,
    const float* __restrict__ h_E,
    const float* __restrict__ Xn,
    const float* __restrict__ mask_V,
    const float* __restrict__ mask_attend,
    const float* __restrict__ bp,
    const float* __restrict__ b1g,
    const float* __restrict__ b2g,
    const float* __restrict__ b3g,
    const float* __restrict__ big,
    const float* __restrict__ bog,
    const float* __restrict__ g1,
    const float* __restrict__ be1,
    const float* __restrict__ g2,
    const float* __restrict__ be2,
    const unsigned short* __restrict__ wsT,
    float* __restrict__ out) {

    __shared__ __align__(16) unsigned short lds[4928];   // 9856 B

    const int tid  = threadIdx.x;
    const int wv   = tid >> 6;
    const int lane = tid & 63;
    const int quad = lane >> 4;
    const int l16  = lane & 15;
    const int ko   = quad * 8;
    const int site = blockIdx.x;
    const int rowB = wv * 16;            // this wave's K-row base

    unsigned short* buf1 = lds;
    unsigned short* geoF = lds + GEOF_OFF;
    float*          Fv   = (float*)lds;

    const unsigned short* W1F = wsT + W1F_OFF;
    const unsigned short* W2F = wsT + W2F_OFF;
    const unsigned short* W3F = wsT + W3F_OFF;
    const unsigned short* WiF = wsT + WIF_OFF;
    const unsigned short* WoF = wsT + WOF_OFF;
    const unsigned short* WpF = wsT + WPF_OFF;

    const float* hEb = h_E + (size_t)site * HES;
    const float* hVb = h_V + site * 128;
    const short8 z8 = {0, 0, 0, 0, 0, 0, 0, 0};
    const int rA = rowB + l16;           // this lane's A-row for fragments

    // ---- frames in registers: wave wv handles k = rowB + l16 (lanes 0..15) ----
    const int kf = rowB + l16;
    const bool fActive = (lane < 16) && (kf < K_);
    float Rr[9], Tt[3];
    if (fActive) {
        const float* xp = Xn + ((size_t)site * K_ + kf) * 9;
        float Nx = xp[0], Ny = xp[1], Nz = xp[2];
        float Ax = xp[3], Ay = xp[4], Az = xp[5];
        float Cx = xp[6], Cy = xp[7], Cz = xp[8];
        float e0x = Ax - Nx, e0y = Ay - Ny, e0z = Az - Nz;
        float r0 = 1.0f / sqrtf(e0x * e0x + e0y * e0y + e0z * e0z + 1e-8f);
        e0x *= r0; e0y *= r0; e0z *= r0;
        float u1x = Cx - Ax, u1y = Cy - Ay, u1z = Cz - Az;
        float d = e0x * u1x + e0y * u1y + e0z * u1z;
        u1x -= e0x * d; u1y -= e0y * d; u1z -= e0z * d;
        float r1 = 1.0f / sqrtf(u1x * u1x + u1y * u1y + u1z * u1z + 1e-8f);
        u1x *= r1; u1y *= r1; u1z *= r1;
        Rr[0] = e0x; Rr[1] = u1x; Rr[2] = e0y * u1z - e0z * u1y;
        Rr[3] = e0y; Rr[4] = u1y; Rr[5] = e0z * u1x - e0x * u1z;
        Rr[6] = e0z; Rr[7] = u1z; Rr[8] = e0x * u1y - e0y * u1x;
        Tt[0] = Ax; Tt[1] = Ay; Tt[2] = Az;
    }

    // ---- p_ln MFMA (row-split: 1 rt per wave) -> PlFull LDS ----
    {
        floatx4 a[2] = {{0,0,0,0},{0,0,0,0}};
        for (int kc = 0; kc < 4; ++kc) {
            int col = 256 + kc * 32 + ko;
            short8 fa = (rA < K_) ? pack8(hEb + rA * NIN_ + col) : z8;
            for (int ct = 0; ct < 2; ++ct) {
                short8 fb = *(const short8*)(WpF + (ct * 4 + kc) * 512 + lane * 8);
                a[ct] = __builtin_amdgcn_mfma_f32_16x16x32_bf16(fa, fb, a[ct], 0, 0, 0);
            }
        }
        for (int ct = 0; ct < 2; ++ct) {
            int ccol = ct * 16 + l16;
            if (ccol < 24) {
                float bpc = bp[ccol];
                for (int i = 0; i < 4; ++i) {
                    int row = rowB + quad * 4 + i;
                    if (row < K_) Fv[PLF_OFF + row * 24 + ccol] = a[ct][i] + bpc;
                }
            }
        }
    }

    // ---- npg by lane k (own rows only; same-wave LDS ordering suffices) ----
    if (fActive) {
        float pl[24];
        #pragma unroll
        for (int c = 0; c < 24; ++c) pl[c] = Fv[PLF_OFF + kf * 24 + c];
        if (kf == 0) {
            #pragma unroll
            for (int i = 0; i < 9; ++i) Fv[R0_OFF + i] = Rr[i];
            Fv[T0_OFF] = Tt[0]; Fv[T0_OFF + 1] = Tt[1]; Fv[T0_OFF + 2] = Tt[2];
            #pragma unroll
            for (int c = 0; c < 24; ++c) Fv[PL0_OFF + c] = pl[c];
        }
        #pragma unroll
        for (int n = 0; n < 8; ++n) {
            float p0 = pl[n * 3], p1 = pl[n * 3 + 1], p2 = pl[n * 3 + 2];
            #pragma unroll
            for (int i = 0; i < 3; ++i)
                Fv[NPG_OFF + kf * 24 + n * 3 + i] =
                    Rr[i * 3 + 0] * p0 + Rr[i * 3 + 1] * p1 + Rr[i * 3 + 2] * p2 + Tt[i];
        }
    }
    __syncthreads();   // sync1: Npg/R0/T0/Pl0 complete before cross-wave geoF reads

    // ---- features -> geoF (overlays dead PlFull), split over 128 threads ----
    for (int id = tid; id < 720; id += 128) geoF[(id / 24) * GFW + 72 + id % 24] = 0;
    {
        float R00 = Fv[0], R01 = Fv[1], R02 = Fv[2], R03 = Fv[3], R04 = Fv[4];
        float R05 = Fv[5], R06 = Fv[6], R07 = Fv[7], R08 = Fv[8];
        float T00 = Fv[9], T01 = Fv[10], T02 = Fv[11];
        for (int id = tid; id < 240; id += 128) {
            int k = id >> 3, n = id & 7;
            float p0 = Fv[PL0_OFF + n * 3], p1 = Fv[PL0_OFF + n * 3 + 1], p2 = Fv[PL0_OFF + n * 3 + 2];
            float q0g = Fv[NPG_OFF + n * 3], q1g = Fv[NPG_OFF + n * 3 + 1], q2g = Fv[NPG_OFF + n * 3 + 2];
            float a0 = Fv[NPG_OFF + k * 24 + n * 3];
            float a1 = Fv[NPG_OFF + k * 24 + n * 3 + 1];
            float a2 = Fv[NPG_OFF + k * 24 + n * 3 + 2];
            float d0 = a0 - T00, d1 = a1 - T01, d2 = a2 - T02;
            float nl0 = R00 * d0 + R03 * d1 + R06 * d2;
            float nl1 = R01 * d0 + R04 * d1 + R07 * d2;
            float nl2 = R02 * d0 + R05 * d1 + R08 * d2;
            unsigned short* gf = geoF + k * GFW;
            gf[0 + n * 3] = f2b(p0); gf[1 + n * 3] = f2b(p1); gf[2 + n * 3] = f2b(p2);
            gf[24 + n] = f2b(sqrtf(p0 * p0 + p1 * p1 + p2 * p2 + 1e-8f));
            gf[32 + n * 3] = f2b(nl0); gf[33 + n * 3] = f2b(nl1); gf[34 + n * 3] = f2b(nl2);
            gf[56 + n] = f2b(sqrtf(nl0 * nl0 + nl1 * nl1 + nl2 * nl2 + 1e-8f));
            float q0 = q0g - a0, q1 = q1g - a1, q2 = q2g - a2;
            gf[64 + n] = f2b(sqrtf(q0 * q0 + q1 * q1 + q2 * q2 + 1e-8f));
        }
    }
    __syncthreads();   // sync2: geoF complete before stage-1 fragment preloads

    // ---- stage 1: own rows @ W1 -> gelu -> buf1 (two ct-passes, acc[4]) ----
    {
        // preload this wave's 3 geoF fragments; barrier so buf1 writes below
        // can't clobber the other wave's geoF rows before it has them in regs.
        short8 gfa[3];
        for (int kc = 0; kc < 3; ++kc)
            gfa[kc] = (rA < K_) ? *(const short8*)&geoF[rA * GFW + kc * 32 + ko] : z8;
        __syncthreads();   // sync3

        for (int p = 0; p < 2; ++p) {
            floatx4 acc[4];
            for (int t = 0; t < 4; ++t) acc[t] = (floatx4){0,0,0,0};
            for (int kc = 0; kc < 4; ++kc) {            // kcg 0..3: h_V (rows identical)
                int col = kc * 32 + ko;
                short8 fa = pack8(hVb + col);
                for (int t = 0; t < 4; ++t) {
                    short8 fb = *(const short8*)(W1F + ((p * 4 + t) * 19 + kc) * 512 + lane * 8);
                    acc[t] = __builtin_amdgcn_mfma_f32_16x16x32_bf16(fa, fb, acc[t], 0, 0, 0);
                }
            }
            for (int kc = 0; kc < 12; ++kc) {           // kcg 4..15: h_E (own rows)
                int col = kc * 32 + ko;
                short8 fa = (rA < K_) ? pack8(hEb + rA * NIN_ + col) : z8;
                for (int t = 0; t < 4; ++t) {
                    short8 fb = *(const short8*)(W1F + ((p * 4 + t) * 19 + 4 + kc) * 512 + lane * 8);
                    acc[t] = __builtin_amdgcn_mfma_f32_16x16x32_bf16(fa, fb, acc[t], 0, 0, 0);
                }
            }
            for (int kc = 0; kc < 3; ++kc) {            // kcg 16..18: geoF (regs)
                for (int t = 0; t < 4; ++t) {
                    short8 fb = *(const short8*)(W1F + ((p * 4 + t) * 19 + 16 + kc) * 512 + lane * 8);
                    acc[t] = __builtin_amdgcn_mfma_f32_16x16x32_bf16(gfa[kc], fb, acc[t], 0, 0, 0);
                }
            }
            for (int t = 0; t < 4; ++t) {
                int col = (p * 4 + t) * 16 + l16;
                float bb = b1g[col];
                for (int r = 0; r < 4; ++r) {
                    int row = rowB + quad * 4 + r;
                    buf1[row * BUFW + col] = f2b(gelu_f(acc[t][r] + bb));
                }
            }
        }
    }

    // ---- stage 2: own buf1 rows @ W2 -> gelu -> buf1 (no cross-wave sync) ----
    {
        short8 Af[4];
        for (int kc = 0; kc < 4; ++kc)
            Af[kc] = *(const short8*)&buf1[rA * BUFW + kc * 32 + ko];
        for (int p = 0; p < 2; ++p) {
            floatx4 acc[4];
            for (int t = 0; t < 4; ++t) acc[t] = (floatx4){0,0,0,0};
            for (int kc = 0; kc < 4; ++kc)
                for (int t = 0; t < 4; ++t) {
                    short8 fb = *(const short8*)(W2F + ((p * 4 + t) * 4 + kc) * 512 + lane * 8);
                    acc[t] = __builtin_amdgcn_mfma_f32_16x16x32_bf16(Af[kc], fb, acc[t], 0, 0, 0);
                }
            for (int t = 0; t < 4; ++t) {
                int col = (p * 4 + t) * 16 + l16;
                float bb = b2g[col];
                for (int r = 0; r < 4; ++r) {
                    int row = rowB + quad * 4 + r;
                    buf1[row * BUFW + col] = f2b(gelu_f(acc[t][r] + bb));
                }
            }
        }
    }

    // ---- stage 3: own buf1 rows @ W3 + b3 -> masked partial mean -> NM[wv] ----
    {
        short8 Af[4];
        for (int kc = 0; kc < 4; ++kc)
            Af[kc] = *(const short8*)&buf1[rA * BUFW + kc * 32 + ko];
        float maskR[4];
        for (int r = 0; r < 4; ++r) {
            int row = rowB + quad * 4 + r;
            maskR[r] = (row < K_) ? mask_attend[site * K_ + row] * (1.0f / 30.0f) : 0.0f;
        }
        const int nmo = wv ? NM1_OFF : NM0_OFF;
        for (int p = 0; p < 2; ++p) {
            floatx4 acc[4];
            for (int t = 0; t < 4; ++t) acc[t] = (floatx4){0,0,0,0};
            for (int kc = 0; kc < 4; ++kc)
                for (int t = 0; t < 4; ++t) {
                    short8 fb = *(const short8*)(W3F + ((p * 4 + t) * 4 + kc) * 512 + lane * 8);
                    acc[t] = __builtin_amdgcn_mfma_f32_16x16x32_bf16(Af[kc], fb, acc[t], 0, 0, 0);
                }
            for (int t = 0; t < 4; ++t) {
                int col = (p * 4 + t) * 16 + l16;
                float bb = b3g[col];
                float cs = 0.0f;
                for (int r = 0; r < 4; ++r)
                    cs += (acc[t][r] + bb) * maskR[r];
                cs += __shfl_xor(cs, 16, 64);
                cs += __shfl_xor(cs, 32, 64);
                if (lane < 16) Fv[nmo + col] = cs;
            }
        }
    }
    __syncthreads();   // sync4: both nm partials ready; buf1 fully dead

    // ---- tail: LN1 -> FFN -> LN2 -> out, col-split over 128 threads ----
    {
        int c = tid;
        float xb = hVb[c] + Fv[NM0_OFF + c] + Fv[NM1_OFF + c];
        float s = xb, q = xb * xb;
        for (int o = 32; o; o >>= 1) { s += __shfl_xor(s, o, 64); q += __shfl_xor(q, o, 64); }
        if (lane == 0) { Fv[LNP_OFF + wv * 2] = s; Fv[LNP_OFF + wv * 2 + 1] = q; }
        __syncthreads();   // sync5
        float sT = Fv[LNP_OFF + 0] + Fv[LNP_OFF + 2];
        float qT = Fv[LNP_OFF + 1] + Fv[LNP_OFF + 3];
        float m = sT * (1.0f / 128.0f);
        float inv = 1.0f / sqrtf(qT * (1.0f / 128.0f) - m * m + 1e-5f);
        float h = (xb - m) * inv * g1[c] + be1[c];
        Fv[HARR_OFF + c] = h;
        __syncthreads();   // sync6: h complete before cross-wave FFN1 reads

        // FFN1: 4 outputs per thread, coalesced WiF [c8][o][8]
        for (int j = 0; j < 4; ++j) {
            int o = tid + 128 * j;
            float sa = big[o], sb = 0.0f;
            for (int c8 = 0; c8 < 16; c8 += 2) {
                ushort8 v0 = *(const ushort8*)(WiF + c8 * 4096 + o * 8);
                ushort8 v1 = *(const ushort8*)(WiF + (c8 + 1) * 4096 + o * 8);
                sa += dot8(&Fv[HARR_OFF + c8 * 8], v0);
                sb += dot8(&Fv[HARR_OFF + c8 * 8 + 8], v1);
            }
            Fv[GARR_OFF + o] = gelu_f(sa + sb);
        }
        __syncthreads();   // sync7: g complete before cross-wave FFN2 reads

        // FFN2: 1 output per thread, coalesced WoF [o8][c][8]
        float d0 = bog[c], d1 = 0.0f;
        for (int o8 = 0; o8 < 64; o8 += 2) {
            ushort8 v0  = *(const ushort8*)(WoF + o8 * 1024 + c * 8);
            ushort8 v0n = *(const ushort8*)(WoF + (o8 + 1) * 1024 + c * 8);
            const float* gp = &Fv[GARR_OFF + o8 * 8];
            d0 += dot8(gp, v0);
            d1 += dot8(gp + 8, v0n);
        }
        float y = h + d0 + d1;
        float s2 = y, q2 = y * y;
        for (int o = 32; o; o >>= 1) { s2 += __shfl_xor(s2, o, 64); q2 += __shfl_xor(q2, o, 64); }
        if (lane == 0) { Fv[LNP_OFF + 4 + wv * 2] = s2; Fv[LNP_OFF + 4 + wv * 2 + 1] = q2; }
        __syncthreads();   // sync8
        float sT2 = Fv[LNP_OFF + 4] + Fv[LNP_OFF + 6];
        float qT2 = Fv[LNP_OFF + 5] + Fv[LNP_OFF + 7];
        float m2 = sT2 * (1.0f / 128.0f);
        float inv2 = 1.0f / sqrtf(qT2 * (1.0f / 128.0f) - m2 * m2 + 1e-5f);
        float mv = mask_V[site];
        out[site * 128 + c] = ((y - m2) * inv2 * g2[c] + be2[c]) * mv;
    }
}

extern "C" void kernel_launch(void* const* d_in, const int* in_sizes, int n_in,
                              void* d_out, int out_size, void* d_ws, size_t ws_size,
                              hipStream_t stream) {
    const float* h_V = (const float*)d_in[0];
    const float* h_E = (const float*)d_in[1];
    // d_in[2] = E_idx (int32, unused by reference)
    const float* Xn  = (const float*)d_in[3];
    const float* mV  = (const float*)d_in[4];
    const float* mA  = (const float*)d_in[5];
    const float* Wp  = (const float*)d_in[6];
    const float* bp  = (const float*)d_in[7];
    const float* W1  = (const float*)d_in[8];
    const float* b1  = (const float*)d_in[9];
    const float* W2  = (const float*)d_in[10];
    const float* b2  = (const float*)d_in[11];
    const float* W3  = (const float*)d_in[12];
    const float* b3  = (const float*)d_in[13];
    const float* Wi  = (const float*)d_in[14];
    const float* bi  = (const float*)d_in[15];
    const float* Wo  = (const float*)d_in[16];
    const float* bo  = (const float*)d_in[17];
    const float* g1  = (const float*)d_in[18];
    const float* be1 = (const float*)d_in[19];
    const float* g2  = (const float*)d_in[20];
    const float* be2 = (const float*)d_in[21];
    unsigned short* ws = (unsigned short*)d_ws;
    float* out = (float*)d_out;

    prep_kernel<<<960, 256, 0, stream>>>(W1, W2, W3, Wi, Wo, Wp, ws);
    main_kernel<<<B_ * L_, 128, 0, stream>>>(h_V, h_E, Xn, mV, mA, bp,
                                             b1, b2, b3, bi, bo,
                                             g1, be1, g2, be2, ws, out);
}

// Round 5
// 685.690 us; speedup vs baseline: 1.0114x; 1.0114x over previous
//
#include <hip/hip_runtime.h>

#define B_ 8
#define L_ 512
#define K_ 30
#define NIN_ 384
#define HES 11520          // floats per site in h_E
#define BUFW 136           // buf1 row stride (ushort)
#define GFW 96             // geoF row stride (ushort)
// f32 indices inside the per-BLOCK arena:
#define R0_OFF 0
#define T0_OFF 9
#define PL0_OFF 12
#define NPG_OFF 40         // Npg[30][24] -> 40..759
#define PLF_OFF 760        // Pl[30][24] -> 760..1479 (dies before geoF)
#define NM0_OFF 2200       // wave0 nm partial
#define NM1_OFF 2328       // wave1 nm partial
#define LNP_OFF 2456       // 8 floats LN cross-wave partials
#define HARR_OFF 0         // tail: h[128] overlays dead buf1
#define GARR_OFF 128       // tail: g[512] overlays dead buf1
// ushort index:
#define GEOF_OFF 1520      // byte 3040, overlays dead PlFull

// ws fragment-ordered weights (ushort, bf16):
#define W1F_OFF 0
#define W2F_OFF 77824
#define W3F_OFF 94208
#define WIF_OFF 110592
#define WOF_OFF 176128
#define WPF_OFF 241664

typedef __attribute__((ext_vector_type(8))) short short8;
typedef __attribute__((ext_vector_type(8))) unsigned short ushort8;
typedef __attribute__((ext_vector_type(4))) float floatx4;
typedef __attribute__((ext_vector_type(4))) float f32x4;
typedef __attribute__((ext_vector_type(4))) unsigned int uint4v;

__device__ __forceinline__ float b2f(unsigned short u) {
    union { unsigned int i; float f; } x; x.i = ((unsigned int)u) << 16; return x.f;
}
__device__ __forceinline__ unsigned short f2b(float f) {
    unsigned int u = __builtin_bit_cast(unsigned int, f);
    return (unsigned short)((u + 0x7fffu + ((u >> 16) & 1u)) >> 16);
}
__device__ __forceinline__ float gelu_f(float x) {
    return 0.5f * x * (1.0f + erff(x * 0.70710678118654752440f));
}
// f32x8 -> bf16x8 via 4x v_cvt_pk_bf16_f32 (RNE)
__device__ __forceinline__ short8 pack8(const float* p) {
    f32x4 lo = *(const f32x4*)p;
    f32x4 hi = *(const f32x4*)(p + 4);
    unsigned int d0, d1, d2, d3;
    asm("v_cvt_pk_bf16_f32 %0, %1, %2" : "=v"(d0) : "v"(lo[0]), "v"(lo[1]));
    asm("v_cvt_pk_bf16_f32 %0, %1, %2" : "=v"(d1) : "v"(lo[2]), "v"(lo[3]));
    asm("v_cvt_pk_bf16_f32 %0, %1, %2" : "=v"(d2) : "v"(hi[0]), "v"(hi[1]));
    asm("v_cvt_pk_bf16_f32 %0, %1, %2" : "=v"(d3) : "v"(hi[2]), "v"(hi[3]));
    uint4v d = {d0, d1, d2, d3};
    return __builtin_bit_cast(short8, d);
}
__device__ __forceinline__ float dot8(const float* hp, ushort8 v) {
    return hp[0] * b2f(v[0]) + hp[1] * b2f(v[1]) + hp[2] * b2f(v[2]) + hp[3] * b2f(v[3]) +
           hp[4] * b2f(v[4]) + hp[5] * b2f(v[5]) + hp[6] * b2f(v[6]) + hp[7] * b2f(v[7]);
}

// One element per thread; grid covers 245760 exactly. (unchanged)
__global__ __launch_bounds__(256) void prep_kernel(
        const float* __restrict__ W1, const float* __restrict__ W2,
        const float* __restrict__ W3, const float* __restrict__ Wi,
        const float* __restrict__ Wo, const float* __restrict__ Wp,
        unsigned short* __restrict__ ws) {
    int idx = blockIdx.x * 256 + threadIdx.x;
    if (idx < 94208 || (idx >= 241664 && idx < 245760)) {
        const float* in; int i, KC, Kreal, Nreal, Nld;
        if (idx < 77824)      { in = W1; i = idx;          KC = 19; Kreal = 584; Nreal = 128; Nld = 128; }
        else if (idx < 94208) { in = W2; i = idx - 77824;  KC = 4;  Kreal = 128; Nreal = 128; Nld = 128; }
        else                  { in = Wp; i = idx - 241664; KC = 4;  Kreal = 128; Nreal = 24;  Nld = 24;  }
        int f = i >> 9, r = i & 511;
        int ct = f / KC, kc = f % KC;
        int lane = r >> 3, j = r & 7;
        int q = lane >> 4, l = lane & 15;
        int k = kc * 32 + q * 8 + j, n = ct * 16 + l;
        ws[idx] = (k < Kreal && n < Nreal) ? f2b(in[k * Nld + n]) : (unsigned short)0;
    } else if (idx < 110592) {
        int i = idx - 94208;
        int f = i >> 9, r = i & 511;
        int ct = f >> 2, kc = f & 3;
        int lane = r >> 3, j = r & 7;
        int q = lane >> 4, l = lane & 15;
        ws[idx] = f2b(W3[(kc * 32 + q * 8 + j) * 128 + ct * 16 + l]);
    } else if (idx < 176128) {
        int i = idx - 110592;
        int c8 = i >> 12, r = i & 4095;
        int o = r >> 3, ii = r & 7;
        ws[idx] = f2b(Wi[(c8 * 8 + ii) * 512 + o]);
    } else if (idx < 241664) {
        int i = idx - 176128;
        int o8 = i >> 10, r = i & 1023;
        int c = r >> 3, ii = r & 7;
        ws[idx] = f2b(Wo[(o8 * 8 + ii) * 128 + c]);
    }
}

// ONE SITE PER BLOCK, 2 cooperating waves, row-split stages, 2-pass ct loops.
// Register-pressure peaks removed: (a) gelu is applied in a low-pressure LDS
// sweep over each wave's own rows, NOT in the MFMA epilogue (the inlined erff
// polynomial was forcing every accumulator to scratch -- R3/R4's identical
// 274 MB WRITE_SIZE); (b) npg streams p_ln from LDS (3 live, not 24).
__global__ __launch_bounds__(128, 4) void main_kernel(
    const float* __restrict__ h_V,
    const float* __restrict__ h_E,
    const float* __restrict__ Xn,
    const float* __restrict__ mask_V,
    const float* __restrict__ mask_attend,
    const float* __restrict__ bp,
    const float* __restrict__ b1g,
    const float* __restrict__ b2g,
    const float* __restrict__ b3g,
    const float* __restrict__ big,
    const float* __restrict__ bog,
    const float* __restrict__ g1,
    const float* __restrict__ be1,
    const float* __restrict__ g2,
    const float* __restrict__ be2,
    const unsigned short* __restrict__ wsT,
    float* __restrict__ out) {

    __shared__ __align__(16) unsigned short lds[4928];   // 9856 B

    const int tid  = threadIdx.x;
    const int wv   = tid >> 6;
    const int lane = tid & 63;
    const int quad = lane >> 4;
    const int l16  = lane & 15;
    const int ko   = quad * 8;
    const int site = blockIdx.x;
    const int rowB = wv * 16;            // this wave's K-row base

    unsigned short* buf1 = lds;
    unsigned short* geoF = lds + GEOF_OFF;
    float*          Fv   = (float*)lds;

    const unsigned short* W1F = wsT + W1F_OFF;
    const unsigned short* W2F = wsT + W2F_OFF;
    const unsigned short* W3F = wsT + W3F_OFF;
    const unsigned short* WiF = wsT + WIF_OFF;
    const unsigned short* WoF = wsT + WOF_OFF;
    const unsigned short* WpF = wsT + WPF_OFF;

    const float* hEb = h_E + (size_t)site * HES;
    const float* hVb = h_V + site * 128;
    const short8 z8 = {0, 0, 0, 0, 0, 0, 0, 0};
    const int rA = rowB + l16;           // this lane's A-row for fragments

    // ---- frames in registers: wave wv handles k = rowB + l16 (lanes 0..15) ----
    const int kf = rowB + l16;
    const bool fActive = (lane < 16) && (kf < K_);
    float Rr[9], Tt[3];
    if (fActive) {
        const float* xp = Xn + ((size_t)site * K_ + kf) * 9;
        float Nx = xp[0], Ny = xp[1], Nz = xp[2];
        float Ax = xp[3], Ay = xp[4], Az = xp[5];
        float Cx = xp[6], Cy = xp[7], Cz = xp[8];
        float e0x = Ax - Nx, e0y = Ay - Ny, e0z = Az - Nz;
        float r0 = 1.0f / sqrtf(e0x * e0x + e0y * e0y + e0z * e0z + 1e-8f);
        e0x *= r0; e0y *= r0; e0z *= r0;
        float u1x = Cx - Ax, u1y = Cy - Ay, u1z = Cz - Az;
        float d = e0x * u1x + e0y * u1y + e0z * u1z;
        u1x -= e0x * d; u1y -= e0y * d; u1z -= e0z * d;
        float r1 = 1.0f / sqrtf(u1x * u1x + u1y * u1y + u1z * u1z + 1e-8f);
        u1x *= r1; u1y *= r1; u1z *= r1;
        Rr[0] = e0x; Rr[1] = u1x; Rr[2] = e0y * u1z - e0z * u1y;
        Rr[3] = e0y; Rr[4] = u1y; Rr[5] = e0z * u1x - e0x * u1z;
        Rr[6] = e0z; Rr[7] = u1z; Rr[8] = e0x * u1y - e0y * u1x;
        Tt[0] = Ax; Tt[1] = Ay; Tt[2] = Az;
    }

    // ---- p_ln MFMA (row-split: 1 rt per wave) -> PlFull LDS ----
    {
        floatx4 a[2] = {{0,0,0,0},{0,0,0,0}};
        for (int kc = 0; kc < 4; ++kc) {
            int col = 256 + kc * 32 + ko;
            short8 fa = (rA < K_) ? pack8(hEb + rA * NIN_ + col) : z8;
            for (int ct = 0; ct < 2; ++ct) {
                short8 fb = *(const short8*)(WpF + (ct * 4 + kc) * 512 + lane * 8);
                a[ct] = __builtin_amdgcn_mfma_f32_16x16x32_bf16(fa, fb, a[ct], 0, 0, 0);
            }
        }
        for (int ct = 0; ct < 2; ++ct) {
            int ccol = ct * 16 + l16;
            if (ccol < 24) {
                float bpc = bp[ccol];
                for (int i = 0; i < 4; ++i) {
                    int row = rowB + quad * 4 + i;
                    if (row < K_) Fv[PLF_OFF + row * 24 + ccol] = a[ct][i] + bpc;
                }
            }
        }
    }

    // ---- npg by lane k: stream p_ln from LDS (3 live), own rows only ----
    if (fActive) {
        if (kf == 0) {
            #pragma unroll
            for (int i = 0; i < 9; ++i) Fv[R0_OFF + i] = Rr[i];
            Fv[T0_OFF] = Tt[0]; Fv[T0_OFF + 1] = Tt[1]; Fv[T0_OFF + 2] = Tt[2];
            for (int c = 0; c < 24; ++c) Fv[PL0_OFF + c] = Fv[PLF_OFF + c];
        }
        for (int n = 0; n < 8; ++n) {
            float p0 = Fv[PLF_OFF + kf * 24 + n * 3];
            float p1 = Fv[PLF_OFF + kf * 24 + n * 3 + 1];
            float p2 = Fv[PLF_OFF + kf * 24 + n * 3 + 2];
            #pragma unroll
            for (int i = 0; i < 3; ++i)
                Fv[NPG_OFF + kf * 24 + n * 3 + i] =
                    Rr[i * 3 + 0] * p0 + Rr[i * 3 + 1] * p1 + Rr[i * 3 + 2] * p2 + Tt[i];
        }
    }
    __syncthreads();   // sync1: Npg/R0/T0/Pl0 complete before cross-wave geoF reads

    // ---- features -> geoF (overlays dead PlFull), split over 128 threads ----
    for (int id = tid; id < 720; id += 128) geoF[(id / 24) * GFW + 72 + id % 24] = 0;
    {
        float R00 = Fv[0], R01 = Fv[1], R02 = Fv[2], R03 = Fv[3], R04 = Fv[4];
        float R05 = Fv[5], R06 = Fv[6], R07 = Fv[7], R08 = Fv[8];
        float T00 = Fv[9], T01 = Fv[10], T02 = Fv[11];
        for (int id = tid; id < 240; id += 128) {
            int k = id >> 3, n = id & 7;
            float p0 = Fv[PL0_OFF + n * 3], p1 = Fv[PL0_OFF + n * 3 + 1], p2 = Fv[PL0_OFF + n * 3 + 2];
            float q0g = Fv[NPG_OFF + n * 3], q1g = Fv[NPG_OFF + n * 3 + 1], q2g = Fv[NPG_OFF + n * 3 + 2];
            float a0 = Fv[NPG_OFF + k * 24 + n * 3];
            float a1 = Fv[NPG_OFF + k * 24 + n * 3 + 1];
            float a2 = Fv[NPG_OFF + k * 24 + n * 3 + 2];
            float d0 = a0 - T00, d1 = a1 - T01, d2 = a2 - T02;
            float nl0 = R00 * d0 + R03 * d1 + R06 * d2;
            float nl1 = R01 * d0 + R04 * d1 + R07 * d2;
            float nl2 = R02 * d0 + R05 * d1 + R08 * d2;
            unsigned short* gf = geoF + k * GFW;
            gf[0 + n * 3] = f2b(p0); gf[1 + n * 3] = f2b(p1); gf[2 + n * 3] = f2b(p2);
            gf[24 + n] = f2b(sqrtf(p0 * p0 + p1 * p1 + p2 * p2 + 1e-8f));
            gf[32 + n * 3] = f2b(nl0); gf[33 + n * 3] = f2b(nl1); gf[34 + n * 3] = f2b(nl2);
            gf[56 + n] = f2b(sqrtf(nl0 * nl0 + nl1 * nl1 + nl2 * nl2 + 1e-8f));
            float q0 = q0g - a0, q1 = q1g - a1, q2 = q2g - a2;
            gf[64 + n] = f2b(sqrtf(q0 * q0 + q1 * q1 + q2 * q2 + 1e-8f));
        }
    }
    __syncthreads();   // sync2: geoF complete before stage-1 fragment preloads

    // ---- stage 1: own rows @ W1 -> buf1 (raw), then own-row gelu sweep ----
    {
        // preload this wave's 3 geoF fragments; barrier so buf1 writes below
        // can't clobber the other wave's geoF rows before it has them in regs.
        short8 gfa[3];
        for (int kc = 0; kc < 3; ++kc)
            gfa[kc] = (rA < K_) ? *(const short8*)&geoF[rA * GFW + kc * 32 + ko] : z8;
        __syncthreads();   // sync3

        for (int p = 0; p < 2; ++p) {
            floatx4 acc[4];
            for (int t = 0; t < 4; ++t) acc[t] = (floatx4){0,0,0,0};
            for (int kc = 0; kc < 4; ++kc) {            // kcg 0..3: h_V (rows identical)
                int col = kc * 32 + ko;
                short8 fa = pack8(hVb + col);
                for (int t = 0; t < 4; ++t) {
                    short8 fb = *(const short8*)(W1F + ((p * 4 + t) * 19 + kc) * 512 + lane * 8);
                    acc[t] = __builtin_amdgcn_mfma_f32_16x16x32_bf16(fa, fb, acc[t], 0, 0, 0);
                }
            }
            for (int kc = 0; kc < 12; ++kc) {           // kcg 4..15: h_E (own rows)
                int col = kc * 32 + ko;
                short8 fa = (rA < K_) ? pack8(hEb + rA * NIN_ + col) : z8;
                for (int t = 0; t < 4; ++t) {
                    short8 fb = *(const short8*)(W1F + ((p * 4 + t) * 19 + 4 + kc) * 512 + lane * 8);
                    acc[t] = __builtin_amdgcn_mfma_f32_16x16x32_bf16(fa, fb, acc[t], 0, 0, 0);
                }
            }
            for (int kc = 0; kc < 3; ++kc) {            // kcg 16..18: geoF (regs)
                for (int t = 0; t < 4; ++t) {
                    short8 fb = *(const short8*)(W1F + ((p * 4 + t) * 19 + 16 + kc) * 512 + lane * 8);
                    acc[t] = __builtin_amdgcn_mfma_f32_16x16x32_bf16(gfa[kc], fb, acc[t], 0, 0, 0);
                }
            }
            for (int t = 0; t < 4; ++t) {               // RAW epilogue: no gelu here
                int col = (p * 4 + t) * 16 + l16;
                float bb = b1g[col];
                for (int r = 0; r < 4; ++r) {
                    int row = rowB + quad * 4 + r;
                    buf1[row * BUFW + col] = f2b(acc[t][r] + bb);
                }
            }
        }
        // low-pressure gelu sweep over own 16 rows (same-wave, no barrier)
        for (int it = 0; it < 32; ++it) {
            int idx = it * 64 + lane;               // 0..2047
            unsigned short* p = &buf1[(rowB + (idx >> 7)) * BUFW + (idx & 127)];
            *p = f2b(gelu_f(b2f(*p)));
        }
    }

    // ---- stage 2: own buf1 rows @ W2 -> buf1 (raw), then gelu sweep ----
    {
        short8 Af[4];
        for (int kc = 0; kc < 4; ++kc)
            Af[kc] = *(const short8*)&buf1[rA * BUFW + kc * 32 + ko];
        for (int p = 0; p < 2; ++p) {
            floatx4 acc[4];
            for (int t = 0; t < 4; ++t) acc[t] = (floatx4){0,0,0,0};
            for (int kc = 0; kc < 4; ++kc)
                for (int t = 0; t < 4; ++t) {
                    short8 fb = *(const short8*)(W2F + ((p * 4 + t) * 4 + kc) * 512 + lane * 8);
                    acc[t] = __builtin_amdgcn_mfma_f32_16x16x32_bf16(Af[kc], fb, acc[t], 0, 0, 0);
                }
            for (int t = 0; t < 4; ++t) {
                int col = (p * 4 + t) * 16 + l16;
                float bb = b2g[col];
                for (int r = 0; r < 4; ++r) {
                    int row = rowB + quad * 4 + r;
                    buf1[row * BUFW + col] = f2b(acc[t][r] + bb);
                }
            }
        }
        for (int it = 0; it < 32; ++it) {
            int idx = it * 64 + lane;
            unsigned short* p = &buf1[(rowB + (idx >> 7)) * BUFW + (idx & 127)];
            *p = f2b(gelu_f(b2f(*p)));
        }
    }

    // ---- stage 3: own buf1 rows @ W3 + b3 -> masked partial mean -> NM[wv] ----
    {
        short8 Af[4];
        for (int kc = 0; kc < 4; ++kc)
            Af[kc] = *(const short8*)&buf1[rA * BUFW + kc * 32 + ko];
        float maskR[4];
        for (int r = 0; r < 4; ++r) {
            int row = rowB + quad * 4 + r;
            maskR[r] = (row < K_) ? mask_attend[site * K_ + row] * (1.0f / 30.0f) : 0.0f;
        }
        const int nmo = wv ? NM1_OFF : NM0_OFF;
        for (int p = 0; p < 2; ++p) {
            floatx4 acc[4];
            for (int t = 0; t < 4; ++t) acc[t] = (floatx4){0,0,0,0};
            for (int kc = 0; kc < 4; ++kc)
                for (int t = 0; t < 4; ++t) {
                    short8 fb = *(const short8*)(W3F + ((p * 4 + t) * 4 + kc) * 512 + lane * 8);
                    acc[t] = __builtin_amdgcn_mfma_f32_16x16x32_bf16(Af[kc], fb, acc[t], 0, 0, 0);
                }
            for (int t = 0; t < 4; ++t) {
                int col = (p * 4 + t) * 16 + l16;
                float bb = b3g[col];
                float cs = 0.0f;
                for (int r = 0; r < 4; ++r)
                    cs += (acc[t][r] + bb) * maskR[r];
                cs += __shfl_xor(cs, 16, 64);
                cs += __shfl_xor(cs, 32, 64);
                if (lane < 16) Fv[nmo + col] = cs;
            }
        }
    }
    __syncthreads();   // sync4: both nm partials ready; buf1 fully dead

    // ---- tail: LN1 -> FFN -> LN2 -> out, col-split over 128 threads ----
    {
        int c = tid;
        float xb = hVb[c] + Fv[NM0_OFF + c] + Fv[NM1_OFF + c];
        float s = xb, q = xb * xb;
        for (int o = 32; o; o >>= 1) { s += __shfl_xor(s, o, 64); q += __shfl_xor(q, o, 64); }
        if (lane == 0) { Fv[LNP_OFF + wv * 2] = s; Fv[LNP_OFF + wv * 2 + 1] = q; }
        __syncthreads();   // sync5
        float sT = Fv[LNP_OFF + 0] + Fv[LNP_OFF + 2];
        float qT = Fv[LNP_OFF + 1] + Fv[LNP_OFF + 3];
        float m = sT * (1.0f / 128.0f);
        float inv = 1.0f / sqrtf(qT * (1.0f / 128.0f) - m * m + 1e-5f);
        float h = (xb - m) * inv * g1[c] + be1[c];
        Fv[HARR_OFF + c] = h;
        __syncthreads();   // sync6: h complete before cross-wave FFN1 reads

        // FFN1: 4 outputs per thread, coalesced WiF [c8][o][8]
        for (int j = 0; j < 4; ++j) {
            int o = tid + 128 * j;
            float sa = big[o], sb = 0.0f;
            for (int c8 = 0; c8 < 16; c8 += 2) {
                ushort8 v0 = *(const ushort8*)(WiF + c8 * 4096 + o * 8);
                ushort8 v1 = *(const ushort8*)(WiF + (c8 + 1) * 4096 + o * 8);
                sa += dot8(&Fv[HARR_OFF + c8 * 8], v0);
                sb += dot8(&Fv[HARR_OFF + c8 * 8 + 8], v1);
            }
            Fv[GARR_OFF + o] = gelu_f(sa + sb);
        }
        __syncthreads();   // sync7: g complete before cross-wave FFN2 reads

        // FFN2: 1 output per thread, coalesced WoF [o8][c][8]
        float d0 = bog[c], d1 = 0.0f;
        for (int o8 = 0; o8 < 64; o8 += 2) {
            ushort8 v0  = *(const ushort8*)(WoF + o8 * 1024 + c * 8);
            ushort8 v0n = *(const ushort8*)(WoF + (o8 + 1) * 1024 + c * 8);
            const float* gp = &Fv[GARR_OFF + o8 * 8];
            d0 += dot8(gp, v0);
            d1 += dot8(gp + 8, v0n);
        }
        float y = h + d0 + d1;
        float s2 = y, q2 = y * y;
        for (int o = 32; o; o >>= 1) { s2 += __shfl_xor(s2, o, 64); q2 += __shfl_xor(q2, o, 64); }
        if (lane == 0) { Fv[LNP_OFF + 4 + wv * 2] = s2; Fv[LNP_OFF + 4 + wv * 2 + 1] = q2; }
        __syncthreads();   // sync8
        float sT2 = Fv[LNP_OFF + 4] + Fv[LNP_OFF + 6];
        float qT2 = Fv[LNP_OFF + 5] + Fv[LNP_OFF + 7];
        float m2 = sT2 * (1.0f / 128.0f);
        float inv2 = 1.0f / sqrtf(qT2 * (1.0f / 128.0f) - m2 * m2 + 1e-5f);
        float mv = mask_V[site];
        out[site * 128 + c] = ((y - m2) * inv2 * g2[c] + be2[c]) * mv;
    }
}

extern "C" void kernel_launch(void* const* d_in, const int* in_sizes, int n_in,
                              void* d_out, int out_size, void* d_ws, size_t ws_size,
                              hipStream_t stream) {
    const float* h_V = (const float*)d_in[0];
    const float* h_E = (const float*)d_in[1];
    // d_in[2] = E_idx (int32, unused by reference)
    const float* Xn  = (const float*)d_in[3];
    const float* mV  = (const float*)d_in[4];
    const float* mA  = (const float*)d_in[5];
    const float* Wp  = (const float*)d_in[6];
    const float* bp  = (const float*)d_in[7];
    const float* W1  = (const float*)d_in[8];
    const float* b1  = (const float*)d_in[9];
    const float* W2  = (const float*)d_in[10];
    const float* b2  = (const float*)d_in[11];
    const float* W3  = (const float*)d_in[12];
    const float* b3  = (const float*)d_in[13];
    const float* Wi  = (const float*)d_in[14];
    const float* bi  = (const float*)d_in[15];
    const float* Wo  = (const float*)d_in[16];
    const float* bo  = (const float*)d_in[17];
    const float* g1  = (const float*)d_in[18];
    const float* be1 = (const float*)d_in[19];
    const float* g2  = (const float*)d_in[20];
    const float* be2 = (const float*)d_in[21];
    unsigned short* ws = (unsigned short*)d_ws;
    float* out = (float*)d_out;

    prep_kernel<<<960, 256, 0, stream>>>(W1, W2, W3, Wi, Wo, Wp, ws);
    main_kernel<<<B_ * L_, 128, 0, stream>>>(h_V, h_E, Xn, mV, mA, bp,
                                             b1, b2, b3, bi, bo,
                                             g1, be1, g2, be2, ws, out);
}

// Round 6
// 567.717 us; speedup vs baseline: 1.2216x; 1.2078x over previous
//
#include <hip/hip_runtime.h>

#define B_ 8
#define L_ 512
#define K_ 30
#define NIN_ 384
#define HES 11520          // floats per site in h_E
#define BUFW 136           // buf1 row stride (ushort)
#define GFW 96             // geoF row stride (ushort)
// f32 indices inside the per-BLOCK arena:
#define R0_OFF 0
#define T0_OFF 9
#define PL0_OFF 12
#define NPG_OFF 40         // Npg[30][24] -> 40..759
#define PLF_OFF 760        // Pl[30][24] -> 760..1479 (dies before geoF)
#define NM0_OFF 2200       // wave0 nm partial
#define NM1_OFF 2328       // wave1 nm partial
#define LNP_OFF 2456       // 8 floats LN cross-wave partials
#define HARR_OFF 0         // tail: h[128] overlays dead buf1
#define GARR_OFF 128       // tail: g[512] overlays dead buf1
// ushort index:
#define GEOF_OFF 1520      // byte 3040, overlays dead PlFull

// ws fragment-ordered weights (ushort, bf16):
#define W1F_OFF 0
#define W2F_OFF 77824
#define W3F_OFF 94208
#define WIF_OFF 110592
#define WOF_OFF 176128
#define WPF_OFF 241664

typedef __attribute__((ext_vector_type(8))) short short8;
typedef __attribute__((ext_vector_type(8))) unsigned short ushort8;
typedef __attribute__((ext_vector_type(4))) float floatx4;
typedef __attribute__((ext_vector_type(4))) float f32x4;
typedef __attribute__((ext_vector_type(4))) unsigned int uint4v;

__device__ __forceinline__ float b2f(unsigned short u) {
    union { unsigned int i; float f; } x; x.i = ((unsigned int)u) << 16; return x.f;
}
__device__ __forceinline__ unsigned short f2b(float f) {
    unsigned int u = __builtin_bit_cast(unsigned int, f);
    return (unsigned short)((u + 0x7fffu + ((u >> 16) & 1u)) >> 16);
}
__device__ __forceinline__ float gelu_f(float x) {
    return 0.5f * x * (1.0f + erff(x * 0.70710678118654752440f));
}
// f32x8 -> bf16x8 via 4x v_cvt_pk_bf16_f32 (RNE)
__device__ __forceinline__ short8 pack8(const float* p) {
    f32x4 lo = *(const f32x4*)p;
    f32x4 hi = *(const f32x4*)(p + 4);
    unsigned int d0, d1, d2, d3;
    asm("v_cvt_pk_bf16_f32 %0, %1, %2" : "=v"(d0) : "v"(lo[0]), "v"(lo[1]));
    asm("v_cvt_pk_bf16_f32 %0, %1, %2" : "=v"(d1) : "v"(lo[2]), "v"(lo[3]));
    asm("v_cvt_pk_bf16_f32 %0, %1, %2" : "=v"(d2) : "v"(hi[0]), "v"(hi[1]));
    asm("v_cvt_pk_bf16_f32 %0, %1, %2" : "=v"(d3) : "v"(hi[2]), "v"(hi[3]));
    uint4v d = {d0, d1, d2, d3};
    return __builtin_bit_cast(short8, d);
}
__device__ __forceinline__ float dot8(const float* hp, ushort8 v) {
    return hp[0] * b2f(v[0]) + hp[1] * b2f(v[1]) + hp[2] * b2f(v[2]) + hp[3] * b2f(v[3]) +
           hp[4] * b2f(v[4]) + hp[5] * b2f(v[5]) + hp[6] * b2f(v[6]) + hp[7] * b2f(v[7]);
}

// One element per thread; grid covers 245760 exactly. (unchanged)
__global__ __launch_bounds__(256) void prep_kernel(
        const float* __restrict__ W1, const float* __restrict__ W2,
        const float* __restrict__ W3, const float* __restrict__ Wi,
        const float* __restrict__ Wo, const float* __restrict__ Wp,
        unsigned short* __restrict__ ws) {
    int idx = blockIdx.x * 256 + threadIdx.x;
    if (idx < 94208 || (idx >= 241664 && idx < 245760)) {
        const float* in; int i, KC, Kreal, Nreal, Nld;
        if (idx < 77824)      { in = W1; i = idx;          KC = 19; Kreal = 584; Nreal = 128; Nld = 128; }
        else if (idx < 94208) { in = W2; i = idx - 77824;  KC = 4;  Kreal = 128; Nreal = 128; Nld = 128; }
        else                  { in = Wp; i = idx - 241664; KC = 4;  Kreal = 128; Nreal = 24;  Nld = 24;  }
        int f = i >> 9, r = i & 511;
        int ct = f / KC, kc = f % KC;
        int lane = r >> 3, j = r & 7;
        int q = lane >> 4, l = lane & 15;
        int k = kc * 32 + q * 8 + j, n = ct * 16 + l;
        ws[idx] = (k < Kreal && n < Nreal) ? f2b(in[k * Nld + n]) : (unsigned short)0;
    } else if (idx < 110592) {
        int i = idx - 94208;
        int f = i >> 9, r = i & 511;
        int ct = f >> 2, kc = f & 3;
        int lane = r >> 3, j = r & 7;
        int q = lane >> 4, l = lane & 15;
        ws[idx] = f2b(W3[(kc * 32 + q * 8 + j) * 128 + ct * 16 + l]);
    } else if (idx < 176128) {
        int i = idx - 110592;
        int c8 = i >> 12, r = i & 4095;
        int o = r >> 3, ii = r & 7;
        ws[idx] = f2b(Wi[(c8 * 8 + ii) * 512 + o]);
    } else if (idx < 241664) {
        int i = idx - 176128;
        int o8 = i >> 10, r = i & 1023;
        int c = r >> 3, ii = r & 7;
        ws[idx] = f2b(Wo[(o8 * 8 + ii) * 128 + c]);
    }
}

// ONE SITE PER BLOCK, 2 cooperating waves, row-split stages (wave wv owns
// K-rows wv*16..wv*16+15), col-split tail. Single-pass acc[8].
// launch_bounds(128,3): the only spill-free budget this kernel fits
// (VGPR cap series: arg {3,4,6,8} -> {~85,64,40,32}; live set ~80).
// VGPR 65..128 -> 4 waves/SIMD; grid supplies 32 waves/CU for refill.
__global__ __launch_bounds__(128, 3) void main_kernel(
    const float* __restrict__ h_V,
    const float* __restrict__ h_E,
    const float* __restrict__ Xn,
    const float* __restrict__ mask_V,
    const float* __restrict__ mask_attend,
    const float* __restrict__ bp,
    const float* __restrict__ b1g,
    const float* __restrict__ b2g,
    const float* __restrict__ b3g,
    const float* __restrict__ big,
    const float* __restrict__ bog,
    const float* __restrict__ g1,
    const float* __restrict__ be1,
    const float* __restrict__ g2,
    const float* __restrict__ be2,
    const unsigned short* __restrict__ wsT,
    float* __restrict__ out) {

    __shared__ __align__(16) unsigned short lds[4928];   // 9856 B

    const int tid  = threadIdx.x;
    const int wv   = tid >> 6;
    const int lane = tid & 63;
    const int quad = lane >> 4;
    const int l16  = lane & 15;
    const int ko   = quad * 8;
    const int site = blockIdx.x;
    const int rowB = wv * 16;            // this wave's K-row base

    unsigned short* buf1 = lds;
    unsigned short* geoF = lds + GEOF_OFF;
    float*          Fv   = (float*)lds;

    const unsigned short* W1F = wsT + W1F_OFF;
    const unsigned short* W2F = wsT + W2F_OFF;
    const unsigned short* W3F = wsT + W3F_OFF;
    const unsigned short* WiF = wsT + WIF_OFF;
    const unsigned short* WoF = wsT + WOF_OFF;
    const unsigned short* WpF = wsT + WPF_OFF;

    const float* hEb = h_E + (size_t)site * HES;
    const float* hVb = h_V + site * 128;
    const short8 z8 = {0, 0, 0, 0, 0, 0, 0, 0};
    const int rA = rowB + l16;           // this lane's A-row for fragments

    // ---- frames in registers: wave wv handles k = rowB + l16 (lanes 0..15) ----
    const int kf = rowB + l16;
    const bool fActive = (lane < 16) && (kf < K_);
    float Rr[9], Tt[3];
    if (fActive) {
        const float* xp = Xn + ((size_t)site * K_ + kf) * 9;
        float Nx = xp[0], Ny = xp[1], Nz = xp[2];
        float Ax = xp[3], Ay = xp[4], Az = xp[5];
        float Cx = xp[6], Cy = xp[7], Cz = xp[8];
        float e0x = Ax - Nx, e0y = Ay - Ny, e0z = Az - Nz;
        float r0 = 1.0f / sqrtf(e0x * e0x + e0y * e0y + e0z * e0z + 1e-8f);
        e0x *= r0; e0y *= r0; e0z *= r0;
        float u1x = Cx - Ax, u1y = Cy - Ay, u1z = Cz - Az;
        float d = e0x * u1x + e0y * u1y + e0z * u1z;
        u1x -= e0x * d; u1y -= e0y * d; u1z -= e0z * d;
        float r1 = 1.0f / sqrtf(u1x * u1x + u1y * u1y + u1z * u1z + 1e-8f);
        u1x *= r1; u1y *= r1; u1z *= r1;
        Rr[0] = e0x; Rr[1] = u1x; Rr[2] = e0y * u1z - e0z * u1y;
        Rr[3] = e0y; Rr[4] = u1y; Rr[5] = e0z * u1x - e0x * u1z;
        Rr[6] = e0z; Rr[7] = u1z; Rr[8] = e0x * u1y - e0y * u1x;
        Tt[0] = Ax; Tt[1] = Ay; Tt[2] = Az;
    }

    // ---- p_ln MFMA (row-split: 1 rt per wave) -> PlFull LDS ----
    {
        floatx4 a[2] = {{0,0,0,0},{0,0,0,0}};
        for (int kc = 0; kc < 4; ++kc) {
            int col = 256 + kc * 32 + ko;
            short8 fa = (rA < K_) ? pack8(hEb + rA * NIN_ + col) : z8;
            for (int ct = 0; ct < 2; ++ct) {
                short8 fb = *(const short8*)(WpF + (ct * 4 + kc) * 512 + lane * 8);
                a[ct] = __builtin_amdgcn_mfma_f32_16x16x32_bf16(fa, fb, a[ct], 0, 0, 0);
            }
        }
        for (int ct = 0; ct < 2; ++ct) {
            int ccol = ct * 16 + l16;
            if (ccol < 24) {
                float bpc = bp[ccol];
                for (int i = 0; i < 4; ++i) {
                    int row = rowB + quad * 4 + i;
                    if (row < K_) Fv[PLF_OFF + row * 24 + ccol] = a[ct][i] + bpc;
                }
            }
        }
    }

    // ---- npg by lane k: stream p_ln from LDS (3 live), own rows only ----
    if (fActive) {
        if (kf == 0) {
            #pragma unroll
            for (int i = 0; i < 9; ++i) Fv[R0_OFF + i] = Rr[i];
            Fv[T0_OFF] = Tt[0]; Fv[T0_OFF + 1] = Tt[1]; Fv[T0_OFF + 2] = Tt[2];
            for (int c = 0; c < 24; ++c) Fv[PL0_OFF + c] = Fv[PLF_OFF + c];
        }
        for (int n = 0; n < 8; ++n) {
            float p0 = Fv[PLF_OFF + kf * 24 + n * 3];
            float p1 = Fv[PLF_OFF + kf * 24 + n * 3 + 1];
            float p2 = Fv[PLF_OFF + kf * 24 + n * 3 + 2];
            #pragma unroll
            for (int i = 0; i < 3; ++i)
                Fv[NPG_OFF + kf * 24 + n * 3 + i] =
                    Rr[i * 3 + 0] * p0 + Rr[i * 3 + 1] * p1 + Rr[i * 3 + 2] * p2 + Tt[i];
        }
    }
    __syncthreads();   // sync1: Npg/R0/T0/Pl0 complete before cross-wave geoF reads

    // ---- features -> geoF (overlays dead PlFull), split over 128 threads ----
    for (int id = tid; id < 720; id += 128) geoF[(id / 24) * GFW + 72 + id % 24] = 0;
    {
        float R00 = Fv[0], R01 = Fv[1], R02 = Fv[2], R03 = Fv[3], R04 = Fv[4];
        float R05 = Fv[5], R06 = Fv[6], R07 = Fv[7], R08 = Fv[8];
        float T00 = Fv[9], T01 = Fv[10], T02 = Fv[11];
        for (int id = tid; id < 240; id += 128) {
            int k = id >> 3, n = id & 7;
            float p0 = Fv[PL0_OFF + n * 3], p1 = Fv[PL0_OFF + n * 3 + 1], p2 = Fv[PL0_OFF + n * 3 + 2];
            float q0g = Fv[NPG_OFF + n * 3], q1g = Fv[NPG_OFF + n * 3 + 1], q2g = Fv[NPG_OFF + n * 3 + 2];
            float a0 = Fv[NPG_OFF + k * 24 + n * 3];
            float a1 = Fv[NPG_OFF + k * 24 + n * 3 + 1];
            float a2 = Fv[NPG_OFF + k * 24 + n * 3 + 2];
            float d0 = a0 - T00, d1 = a1 - T01, d2 = a2 - T02;
            float nl0 = R00 * d0 + R03 * d1 + R06 * d2;
            float nl1 = R01 * d0 + R04 * d1 + R07 * d2;
            float nl2 = R02 * d0 + R05 * d1 + R08 * d2;
            unsigned short* gf = geoF + k * GFW;
            gf[0 + n * 3] = f2b(p0); gf[1 + n * 3] = f2b(p1); gf[2 + n * 3] = f2b(p2);
            gf[24 + n] = f2b(sqrtf(p0 * p0 + p1 * p1 + p2 * p2 + 1e-8f));
            gf[32 + n * 3] = f2b(nl0); gf[33 + n * 3] = f2b(nl1); gf[34 + n * 3] = f2b(nl2);
            gf[56 + n] = f2b(sqrtf(nl0 * nl0 + nl1 * nl1 + nl2 * nl2 + 1e-8f));
            float q0 = q0g - a0, q1 = q1g - a1, q2 = q2g - a2;
            gf[64 + n] = f2b(sqrtf(q0 * q0 + q1 * q1 + q2 * q2 + 1e-8f));
        }
    }
    __syncthreads();   // sync2: geoF complete before cross-wave stage-1 reads

    // ---- stage 1: own rows of [32 x 608] @ W1 -> gelu -> buf1 ----
    {
        floatx4 acc[8];
        for (int ct = 0; ct < 8; ++ct) acc[ct] = (floatx4){0,0,0,0};
        for (int kc = 0; kc < 4; ++kc) {            // kcg 0..3: h_V (rows identical)
            int col = kc * 32 + ko;
            short8 fa = pack8(hVb + col);
            for (int ct = 0; ct < 8; ++ct) {
                short8 fb = *(const short8*)(W1F + (ct * 19 + kc) * 512 + lane * 8);
                acc[ct] = __builtin_amdgcn_mfma_f32_16x16x32_bf16(fa, fb, acc[ct], 0, 0, 0);
            }
        }
        for (int kc = 0; kc < 12; ++kc) {           // kcg 4..15: h_E (own rows)
            int col = kc * 32 + ko;
            short8 fa = (rA < K_) ? pack8(hEb + rA * NIN_ + col) : z8;
            for (int ct = 0; ct < 8; ++ct) {
                short8 fb = *(const short8*)(W1F + (ct * 19 + 4 + kc) * 512 + lane * 8);
                acc[ct] = __builtin_amdgcn_mfma_f32_16x16x32_bf16(fa, fb, acc[ct], 0, 0, 0);
            }
        }
        for (int kc = 0; kc < 3; ++kc) {            // kcg 16..18: geoF (LDS, own rows)
            int col = kc * 32 + ko;
            short8 fa = (rA < K_) ? *(const short8*)&geoF[rA * GFW + col] : z8;
            for (int ct = 0; ct < 8; ++ct) {
                short8 fb = *(const short8*)(W1F + (ct * 19 + 16 + kc) * 512 + lane * 8);
                acc[ct] = __builtin_amdgcn_mfma_f32_16x16x32_bf16(fa, fb, acc[ct], 0, 0, 0);
            }
        }
        __syncthreads();   // sync3: all geoF reads done before buf1 overwrites geoF bytes
        for (int ct = 0; ct < 8; ++ct) {
            int col = ct * 16 + l16;
            float bb = b1g[col];
            for (int r = 0; r < 4; ++r) {
                int row = rowB + quad * 4 + r;
                buf1[row * BUFW + col] = f2b(gelu_f(acc[ct][r] + bb));
            }
        }
    }

    // ---- stage 2: own buf1 rows @ W2 -> gelu -> buf1 (no cross-wave sync) ----
    {
        short8 Af[4];
        for (int kc = 0; kc < 4; ++kc)
            Af[kc] = *(const short8*)&buf1[rA * BUFW + kc * 32 + ko];
        floatx4 acc[8];
        for (int ct = 0; ct < 8; ++ct) acc[ct] = (floatx4){0,0,0,0};
        for (int kc = 0; kc < 4; ++kc)
            for (int ct = 0; ct < 8; ++ct) {
                short8 fb = *(const short8*)(W2F + (ct * 4 + kc) * 512 + lane * 8);
                acc[ct] = __builtin_amdgcn_mfma_f32_16x16x32_bf16(Af[kc], fb, acc[ct], 0, 0, 0);
            }
        for (int ct = 0; ct < 8; ++ct) {
            int col = ct * 16 + l16;
            float bb = b2g[col];
            for (int r = 0; r < 4; ++r) {
                int row = rowB + quad * 4 + r;
                buf1[row * BUFW + col] = f2b(gelu_f(acc[ct][r] + bb));
            }
        }
    }

    // ---- stage 3: own buf1 rows @ W3 + b3 -> masked partial mean -> NM[wv] ----
    {
        short8 Af[4];
        for (int kc = 0; kc < 4; ++kc)
            Af[kc] = *(const short8*)&buf1[rA * BUFW + kc * 32 + ko];
        floatx4 acc[8];
        for (int ct = 0; ct < 8; ++ct) acc[ct] = (floatx4){0,0,0,0};
        for (int kc = 0; kc < 4; ++kc)
            for (int ct = 0; ct < 8; ++ct) {
                short8 fb = *(const short8*)(W3F + (ct * 4 + kc) * 512 + lane * 8);
                acc[ct] = __builtin_amdgcn_mfma_f32_16x16x32_bf16(Af[kc], fb, acc[ct], 0, 0, 0);
            }
        float maskR[4];
        for (int r = 0; r < 4; ++r) {
            int row = rowB + quad * 4 + r;
            maskR[r] = (row < K_) ? mask_attend[site * K_ + row] * (1.0f / 30.0f) : 0.0f;
        }
        const int nmo = wv ? NM1_OFF : NM0_OFF;
        for (int ct = 0; ct < 8; ++ct) {
            int col = ct * 16 + l16;
            float bb = b3g[col];
            float cs = 0.0f;
            for (int r = 0; r < 4; ++r)
                cs += (acc[ct][r] + bb) * maskR[r];
            cs += __shfl_xor(cs, 16, 64);
            cs += __shfl_xor(cs, 32, 64);
            if (lane < 16) Fv[nmo + col] = cs;
        }
    }
    __syncthreads();   // sync4: both nm partials ready; buf1 fully dead

    // ---- tail: LN1 -> FFN -> LN2 -> out, col-split over 128 threads ----
    {
        int c = tid;
        float xb = hVb[c] + Fv[NM0_OFF + c] + Fv[NM1_OFF + c];
        float s = xb, q = xb * xb;
        for (int o = 32; o; o >>= 1) { s += __shfl_xor(s, o, 64); q += __shfl_xor(q, o, 64); }
        if (lane == 0) { Fv[LNP_OFF + wv * 2] = s; Fv[LNP_OFF + wv * 2 + 1] = q; }
        __syncthreads();   // sync5
        float sT = Fv[LNP_OFF + 0] + Fv[LNP_OFF + 2];
        float qT = Fv[LNP_OFF + 1] + Fv[LNP_OFF + 3];
        float m = sT * (1.0f / 128.0f);
        float inv = 1.0f / sqrtf(qT * (1.0f / 128.0f) - m * m + 1e-5f);
        float h = (xb - m) * inv * g1[c] + be1[c];
        Fv[HARR_OFF + c] = h;
        __syncthreads();   // sync6: h complete before cross-wave FFN1 reads

        // FFN1: 4 outputs per thread, coalesced WiF [c8][o][8]
        for (int j = 0; j < 4; ++j) {
            int o = tid + 128 * j;
            float sa = big[o], sb = 0.0f;
            for (int c8 = 0; c8 < 16; c8 += 2) {
                ushort8 v0 = *(const ushort8*)(WiF + c8 * 4096 + o * 8);
                ushort8 v1 = *(const ushort8*)(WiF + (c8 + 1) * 4096 + o * 8);
                sa += dot8(&Fv[HARR_OFF + c8 * 8], v0);
                sb += dot8(&Fv[HARR_OFF + c8 * 8 + 8], v1);
            }
            Fv[GARR_OFF + o] = gelu_f(sa + sb);
        }
        __syncthreads();   // sync7: g complete before cross-wave FFN2 reads

        // FFN2: 1 output per thread, coalesced WoF [o8][c][8]
        float d0 = bog[c], d1 = 0.0f;
        for (int o8 = 0; o8 < 64; o8 += 2) {
            ushort8 v0  = *(const ushort8*)(WoF + o8 * 1024 + c * 8);
            ushort8 v0n = *(const ushort8*)(WoF + (o8 + 1) * 1024 + c * 8);
            const float* gp = &Fv[GARR_OFF + o8 * 8];
            d0 += dot8(gp, v0);
            d1 += dot8(gp + 8, v0n);
        }
        float y = h + d0 + d1;
        float s2 = y, q2 = y * y;
        for (int o = 32; o; o >>= 1) { s2 += __shfl_xor(s2, o, 64); q2 += __shfl_xor(q2, o, 64); }
        if (lane == 0) { Fv[LNP_OFF + 4 + wv * 2] = s2; Fv[LNP_OFF + 4 + wv * 2 + 1] = q2; }
        __syncthreads();   // sync8
        float sT2 = Fv[LNP_OFF + 4] + Fv[LNP_OFF + 6];
        float qT2 = Fv[LNP_OFF + 5] + Fv[LNP_OFF + 7];
        float m2 = sT2 * (1.0f / 128.0f);
        float inv2 = 1.0f / sqrtf(qT2 * (1.0f / 128.0f) - m2 * m2 + 1e-5f);
        float mv = mask_V[site];
        out[site * 128 + c] = ((y - m2) * inv2 * g2[c] + be2[c]) * mv;
    }
}

extern "C" void kernel_launch(void* const* d_in, const int* in_sizes, int n_in,
                              void* d_out, int out_size, void* d_ws, size_t ws_size,
                              hipStream_t stream) {
    const float* h_V = (const float*)d_in[0];
    const float* h_E = (const float*)d_in[1];
    // d_in[2] = E_idx (int32, unused by reference)
    const float* Xn  = (const float*)d_in[3];
    const float* mV  = (const float*)d_in[4];
    const float* mA  = (const float*)d_in[5];
    const float* Wp  = (const float*)d_in[6];
    const float* bp  = (const float*)d_in[7];
    const float* W1  = (const float*)d_in[8];
    const float* b1  = (const float*)d_in[9];
    const float* W2  = (const float*)d_in[10];
    const float* b2  = (const float*)d_in[11];
    const float* W3  = (const float*)d_in[12];
    const float* b3  = (const float*)d_in[13];
    const float* Wi  = (const float*)d_in[14];
    const float* bi  = (const float*)d_in[15];
    const float* Wo  = (const float*)d_in[16];
    const float* bo  = (const float*)d_in[17];
    const float* g1  = (const float*)d_in[18];
    const float* be1 = (const float*)d_in[19];
    const float* g2  = (const float*)d_in[20];
    const float* be2 = (const float*)d_in[21];
    unsigned short* ws = (unsigned short*)d_ws;
    float* out = (float*)d_out;

    prep_kernel<<<960, 256, 0, stream>>>(W1, W2, W3, Wi, Wo, Wp, ws);
    main_kernel<<<B_ * L_, 128, 0, stream>>>(h_V, h_E, Xn, mV, mA, bp,
                                             b1, b2, b3, bi, bo,
                                             g1, be1, g2, be2, ws, out);
}

// Round 7
// 521.763 us; speedup vs baseline: 1.3292x; 1.0881x over previous
//
#include <hip/hip_runtime.h>

#define B_ 8
#define L_ 512
#define K_ 30
#define NIN_ 384
#define HES 11520          // floats per site in h_E
#define BUFW 136           // buf1 row stride (ushort)
#define GFW 96             // geoF row stride (ushort)
// f32 indices inside the per-BLOCK arena:
#define R0_OFF 0
#define T0_OFF 9
#define PL0_OFF 12
#define NPG_OFF 40         // Npg[30][24] -> 40..759
#define PLF_OFF 760        // Pl[30][24] -> 760..1479 (dies before geoF)
#define NM0_OFF 2200       // wave0 nm partial
#define NM1_OFF 2328       // wave1 nm partial
#define LNP_OFF 2456       // 8 floats LN cross-wave partials
#define HARR_OFF 0         // tail: h[128] overlays dead buf1
#define GARR_OFF 128       // tail: g[512] overlays dead buf1
// ushort index:
#define GEOF_OFF 1520      // byte 3040, overlays dead PlFull

// ws fragment-ordered weights (ushort, bf16):
#define W1F_OFF 0
#define W2F_OFF 77824
#define W3F_OFF 94208
#define WIF_OFF 110592
#define WOF_OFF 176128
#define WPF_OFF 241664

typedef __attribute__((ext_vector_type(8))) short short8;
typedef __attribute__((ext_vector_type(8))) unsigned short ushort8;
typedef __attribute__((ext_vector_type(4))) float floatx4;
typedef __attribute__((ext_vector_type(4))) float f32x4;
typedef __attribute__((ext_vector_type(4))) unsigned int uint4v;

__device__ __forceinline__ float b2f(unsigned short u) {
    union { unsigned int i; float f; } x; x.i = ((unsigned int)u) << 16; return x.f;
}
__device__ __forceinline__ unsigned short f2b(float f) {
    unsigned int u = __builtin_bit_cast(unsigned int, f);
    return (unsigned short)((u + 0x7fffu + ((u >> 16) & 1u)) >> 16);
}
__device__ __forceinline__ float gelu_f(float x) {
    return 0.5f * x * (1.0f + erff(x * 0.70710678118654752440f));
}
// f32x8 -> bf16x8 via 4x v_cvt_pk_bf16_f32 (RNE)
__device__ __forceinline__ short8 pack8(const float* p) {
    f32x4 lo = *(const f32x4*)p;
    f32x4 hi = *(const f32x4*)(p + 4);
    unsigned int d0, d1, d2, d3;
    asm("v_cvt_pk_bf16_f32 %0, %1, %2" : "=v"(d0) : "v"(lo[0]), "v"(lo[1]));
    asm("v_cvt_pk_bf16_f32 %0, %1, %2" : "=v"(d1) : "v"(lo[2]), "v"(lo[3]));
    asm("v_cvt_pk_bf16_f32 %0, %1, %2" : "=v"(d2) : "v"(hi[0]), "v"(hi[1]));
    asm("v_cvt_pk_bf16_f32 %0, %1, %2" : "=v"(d3) : "v"(hi[2]), "v"(hi[3]));
    uint4v d = {d0, d1, d2, d3};
    return __builtin_bit_cast(short8, d);
}
__device__ __forceinline__ float dot8(const float* hp, ushort8 v) {
    return hp[0] * b2f(v[0]) + hp[1] * b2f(v[1]) + hp[2] * b2f(v[2]) + hp[3] * b2f(v[3]) +
           hp[4] * b2f(v[4]) + hp[5] * b2f(v[5]) + hp[6] * b2f(v[6]) + hp[7] * b2f(v[7]);
}

// One element per thread; grid covers 245760 exactly. (unchanged)
__global__ __launch_bounds__(256) void prep_kernel(
        const float* __restrict__ W1, const float* __restrict__ W2,
        const float* __restrict__ W3, const float* __restrict__ Wi,
        const float* __restrict__ Wo, const float* __restrict__ Wp,
        unsigned short* __restrict__ ws) {
    int idx = blockIdx.x * 256 + threadIdx.x;
    if (idx < 94208 || (idx >= 241664 && idx < 245760)) {
        const float* in; int i, KC, Kreal, Nreal, Nld;
        if (idx < 77824)      { in = W1; i = idx;          KC = 19; Kreal = 584; Nreal = 128; Nld = 128; }
        else if (idx < 94208) { in = W2; i = idx - 77824;  KC = 4;  Kreal = 128; Nreal = 128; Nld = 128; }
        else                  { in = Wp; i = idx - 241664; KC = 4;  Kreal = 128; Nreal = 24;  Nld = 24;  }
        int f = i >> 9, r = i & 511;
        int ct = f / KC, kc = f % KC;
        int lane = r >> 3, j = r & 7;
        int q = lane >> 4, l = lane & 15;
        int k = kc * 32 + q * 8 + j, n = ct * 16 + l;
        ws[idx] = (k < Kreal && n < Nreal) ? f2b(in[k * Nld + n]) : (unsigned short)0;
    } else if (idx < 110592) {
        int i = idx - 94208;
        int f = i >> 9, r = i & 511;
        int ct = f >> 2, kc = f & 3;
        int lane = r >> 3, j = r & 7;
        int q = lane >> 4, l = lane & 15;
        ws[idx] = f2b(W3[(kc * 32 + q * 8 + j) * 128 + ct * 16 + l]);
    } else if (idx < 176128) {
        int i = idx - 110592;
        int c8 = i >> 12, r = i & 4095;
        int o = r >> 3, ii = r & 7;
        ws[idx] = f2b(Wi[(c8 * 8 + ii) * 512 + o]);
    } else if (idx < 241664) {
        int i = idx - 176128;
        int o8 = i >> 10, r = i & 1023;
        int c = r >> 3, ii = r & 7;
        ws[idx] = f2b(Wo[(o8 * 8 + ii) * 128 + c]);
    }
}

// ONE SITE PER BLOCK, 2 cooperating waves, row-split stages (wave wv owns
// K-rows wv*16..wv*16+15), col-split tail. Single-pass acc[8].
// launch_bounds(128,2): cap=128 VGPR. Occupancy quantizes at 64/128/256
// (16 waves/CU anywhere in 65..128), so a cap of 85 (arg=3) bought nothing
// but 164 MB of spill. ≤64 is proven unreachable (R1/R2/R4/R5). This is
// the spill-free config at the same 16-waves/CU tier.
__global__ __launch_bounds__(128, 2) void main_kernel(
    const float* __restrict__ h_V,
    const float* __restrict__ h_E,
    const float* __restrict__ Xn,
    const float* __restrict__ mask_V,
    const float* __restrict__ mask_attend,
    const float* __restrict__ bp,
    const float* __restrict__ b1g,
    const float* __restrict__ b2g,
    const float* __restrict__ b3g,
    const float* __restrict__ big,
    const float* __restrict__ bog,
    const float* __restrict__ g1,
    const float* __restrict__ be1,
    const float* __restrict__ g2,
    const float* __restrict__ be2,
    const unsigned short* __restrict__ wsT,
    float* __restrict__ out) {

    __shared__ __align__(16) unsigned short lds[4928];   // 9856 B

    const int tid  = threadIdx.x;
    const int wv   = tid >> 6;
    const int lane = tid & 63;
    const int quad = lane >> 4;
    const int l16  = lane & 15;
    const int ko   = quad * 8;
    const int site = blockIdx.x;
    const int rowB = wv * 16;            // this wave's K-row base

    unsigned short* buf1 = lds;
    unsigned short* geoF = lds + GEOF_OFF;
    float*          Fv   = (float*)lds;

    const unsigned short* W1F = wsT + W1F_OFF;
    const unsigned short* W2F = wsT + W2F_OFF;
    const unsigned short* W3F = wsT + W3F_OFF;
    const unsigned short* WiF = wsT + WIF_OFF;
    const unsigned short* WoF = wsT + WOF_OFF;
    const unsigned short* WpF = wsT + WPF_OFF;

    const float* hEb = h_E + (size_t)site * HES;
    const float* hVb = h_V + site * 128;
    const short8 z8 = {0, 0, 0, 0, 0, 0, 0, 0};
    const int rA = rowB + l16;           // this lane's A-row for fragments

    // ---- frames in registers: wave wv handles k = rowB + l16 (lanes 0..15) ----
    const int kf = rowB + l16;
    const bool fActive = (lane < 16) && (kf < K_);
    float Rr[9], Tt[3];
    if (fActive) {
        const float* xp = Xn + ((size_t)site * K_ + kf) * 9;
        float Nx = xp[0], Ny = xp[1], Nz = xp[2];
        float Ax = xp[3], Ay = xp[4], Az = xp[5];
        float Cx = xp[6], Cy = xp[7], Cz = xp[8];
        float e0x = Ax - Nx, e0y = Ay - Ny, e0z = Az - Nz;
        float r0 = 1.0f / sqrtf(e0x * e0x + e0y * e0y + e0z * e0z + 1e-8f);
        e0x *= r0; e0y *= r0; e0z *= r0;
        float u1x = Cx - Ax, u1y = Cy - Ay, u1z = Cz - Az;
        float d = e0x * u1x + e0y * u1y + e0z * u1z;
        u1x -= e0x * d; u1y -= e0y * d; u1z -= e0z * d;
        float r1 = 1.0f / sqrtf(u1x * u1x + u1y * u1y + u1z * u1z + 1e-8f);
        u1x *= r1; u1y *= r1; u1z *= r1;
        Rr[0] = e0x; Rr[1] = u1x; Rr[2] = e0y * u1z - e0z * u1y;
        Rr[3] = e0y; Rr[4] = u1y; Rr[5] = e0z * u1x - e0x * u1z;
        Rr[6] = e0z; Rr[7] = u1z; Rr[8] = e0x * u1y - e0y * u1x;
        Tt[0] = Ax; Tt[1] = Ay; Tt[2] = Az;
    }

    // ---- p_ln MFMA (row-split: 1 rt per wave) -> PlFull LDS ----
    {
        floatx4 a[2] = {{0,0,0,0},{0,0,0,0}};
        for (int kc = 0; kc < 4; ++kc) {
            int col = 256 + kc * 32 + ko;
            short8 fa = (rA < K_) ? pack8(hEb + rA * NIN_ + col) : z8;
            for (int ct = 0; ct < 2; ++ct) {
                short8 fb = *(const short8*)(WpF + (ct * 4 + kc) * 512 + lane * 8);
                a[ct] = __builtin_amdgcn_mfma_f32_16x16x32_bf16(fa, fb, a[ct], 0, 0, 0);
            }
        }
        for (int ct = 0; ct < 2; ++ct) {
            int ccol = ct * 16 + l16;
            if (ccol < 24) {
                float bpc = bp[ccol];
                for (int i = 0; i < 4; ++i) {
                    int row = rowB + quad * 4 + i;
                    if (row < K_) Fv[PLF_OFF + row * 24 + ccol] = a[ct][i] + bpc;
                }
            }
        }
    }

    // ---- npg by lane k: stream p_ln from LDS (3 live), own rows only ----
    if (fActive) {
        if (kf == 0) {
            #pragma unroll
            for (int i = 0; i < 9; ++i) Fv[R0_OFF + i] = Rr[i];
            Fv[T0_OFF] = Tt[0]; Fv[T0_OFF + 1] = Tt[1]; Fv[T0_OFF + 2] = Tt[2];
            for (int c = 0; c < 24; ++c) Fv[PL0_OFF + c] = Fv[PLF_OFF + c];
        }
        for (int n = 0; n < 8; ++n) {
            float p0 = Fv[PLF_OFF + kf * 24 + n * 3];
            float p1 = Fv[PLF_OFF + kf * 24 + n * 3 + 1];
            float p2 = Fv[PLF_OFF + kf * 24 + n * 3 + 2];
            #pragma unroll
            for (int i = 0; i < 3; ++i)
                Fv[NPG_OFF + kf * 24 + n * 3 + i] =
                    Rr[i * 3 + 0] * p0 + Rr[i * 3 + 1] * p1 + Rr[i * 3 + 2] * p2 + Tt[i];
        }
    }
    __syncthreads();   // sync1: Npg/R0/T0/Pl0 complete before cross-wave geoF reads

    // ---- features -> geoF (overlays dead PlFull), split over 128 threads ----
    for (int id = tid; id < 720; id += 128) geoF[(id / 24) * GFW + 72 + id % 24] = 0;
    {
        float R00 = Fv[0], R01 = Fv[1], R02 = Fv[2], R03 = Fv[3], R04 = Fv[4];
        float R05 = Fv[5], R06 = Fv[6], R07 = Fv[7], R08 = Fv[8];
        float T00 = Fv[9], T01 = Fv[10], T02 = Fv[11];
        for (int id = tid; id < 240; id += 128) {
            int k = id >> 3, n = id & 7;
            float p0 = Fv[PL0_OFF + n * 3], p1 = Fv[PL0_OFF + n * 3 + 1], p2 = Fv[PL0_OFF + n * 3 + 2];
            float q0g = Fv[NPG_OFF + n * 3], q1g = Fv[NPG_OFF + n * 3 + 1], q2g = Fv[NPG_OFF + n * 3 + 2];
            float a0 = Fv[NPG_OFF + k * 24 + n * 3];
            float a1 = Fv[NPG_OFF + k * 24 + n * 3 + 1];
            float a2 = Fv[NPG_OFF + k * 24 + n * 3 + 2];
            float d0 = a0 - T00, d1 = a1 - T01, d2 = a2 - T02;
            float nl0 = R00 * d0 + R03 * d1 + R06 * d2;
            float nl1 = R01 * d0 + R04 * d1 + R07 * d2;
            float nl2 = R02 * d0 + R05 * d1 + R08 * d2;
            unsigned short* gf = geoF + k * GFW;
            gf[0 + n * 3] = f2b(p0); gf[1 + n * 3] = f2b(p1); gf[2 + n * 3] = f2b(p2);
            gf[24 + n] = f2b(sqrtf(p0 * p0 + p1 * p1 + p2 * p2 + 1e-8f));
            gf[32 + n * 3] = f2b(nl0); gf[33 + n * 3] = f2b(nl1); gf[34 + n * 3] = f2b(nl2);
            gf[56 + n] = f2b(sqrtf(nl0 * nl0 + nl1 * nl1 + nl2 * nl2 + 1e-8f));
            float q0 = q0g - a0, q1 = q1g - a1, q2 = q2g - a2;
            gf[64 + n] = f2b(sqrtf(q0 * q0 + q1 * q1 + q2 * q2 + 1e-8f));
        }
    }
    __syncthreads();   // sync2: geoF complete before cross-wave stage-1 reads

    // ---- stage 1: own rows of [32 x 608] @ W1 -> gelu -> buf1 ----
    {
        floatx4 acc[8];
        for (int ct = 0; ct < 8; ++ct) acc[ct] = (floatx4){0,0,0,0};
        for (int kc = 0; kc < 4; ++kc) {            // kcg 0..3: h_V (rows identical)
            int col = kc * 32 + ko;
            short8 fa = pack8(hVb + col);
            for (int ct = 0; ct < 8; ++ct) {
                short8 fb = *(const short8*)(W1F + (ct * 19 + kc) * 512 + lane * 8);
                acc[ct] = __builtin_amdgcn_mfma_f32_16x16x32_bf16(fa, fb, acc[ct], 0, 0, 0);
            }
        }
        for (int kc = 0; kc < 12; ++kc) {           // kcg 4..15: h_E (own rows)
            int col = kc * 32 + ko;
            short8 fa = (rA < K_) ? pack8(hEb + rA * NIN_ + col) : z8;
            for (int ct = 0; ct < 8; ++ct) {
                short8 fb = *(const short8*)(W1F + (ct * 19 + 4 + kc) * 512 + lane * 8);
                acc[ct] = __builtin_amdgcn_mfma_f32_16x16x32_bf16(fa, fb, acc[ct], 0, 0, 0);
            }
        }
        for (int kc = 0; kc < 3; ++kc) {            // kcg 16..18: geoF (LDS, own rows)
            int col = kc * 32 + ko;
            short8 fa = (rA < K_) ? *(const short8*)&geoF[rA * GFW + col] : z8;
            for (int ct = 0; ct < 8; ++ct) {
                short8 fb = *(const short8*)(W1F + (ct * 19 + 16 + kc) * 512 + lane * 8);
                acc[ct] = __builtin_amdgcn_mfma_f32_16x16x32_bf16(fa, fb, acc[ct], 0, 0, 0);
            }
        }
        __syncthreads();   // sync3: all geoF reads done before buf1 overwrites geoF bytes
        for (int ct = 0; ct < 8; ++ct) {
            int col = ct * 16 + l16;
            float bb = b1g[col];
            for (int r = 0; r < 4; ++r) {
                int row = rowB + quad * 4 + r;
                buf1[row * BUFW + col] = f2b(gelu_f(acc[ct][r] + bb));
            }
        }
    }

    // ---- stage 2: own buf1 rows @ W2 -> gelu -> buf1 (no cross-wave sync) ----
    {
        short8 Af[4];
        for (int kc = 0; kc < 4; ++kc)
            Af[kc] = *(const short8*)&buf1[rA * BUFW + kc * 32 + ko];
        floatx4 acc[8];
        for (int ct = 0; ct < 8; ++ct) acc[ct] = (floatx4){0,0,0,0};
        for (int kc = 0; kc < 4; ++kc)
            for (int ct = 0; ct < 8; ++ct) {
                short8 fb = *(const short8*)(W2F + (ct * 4 + kc) * 512 + lane * 8);
                acc[ct] = __builtin_amdgcn_mfma_f32_16x16x32_bf16(Af[kc], fb, acc[ct], 0, 0, 0);
            }
        for (int ct = 0; ct < 8; ++ct) {
            int col = ct * 16 + l16;
            float bb = b2g[col];
            for (int r = 0; r < 4; ++r) {
                int row = rowB + quad * 4 + r;
                buf1[row * BUFW + col] = f2b(gelu_f(acc[ct][r] + bb));
            }
        }
    }

    // ---- stage 3: own buf1 rows @ W3 + b3 -> masked partial mean -> NM[wv] ----
    {
        short8 Af[4];
        for (int kc = 0; kc < 4; ++kc)
            Af[kc] = *(const short8*)&buf1[rA * BUFW + kc * 32 + ko];
        floatx4 acc[8];
        for (int ct = 0; ct < 8; ++ct) acc[ct] = (floatx4){0,0,0,0};
        for (int kc = 0; kc < 4; ++kc)
            for (int ct = 0; ct < 8; ++ct) {
                short8 fb = *(const short8*)(W3F + (ct * 4 + kc) * 512 + lane * 8);
                acc[ct] = __builtin_amdgcn_mfma_f32_16x16x32_bf16(Af[kc], fb, acc[ct], 0, 0, 0);
            }
        float maskR[4];
        for (int r = 0; r < 4; ++r) {
            int row = rowB + quad * 4 + r;
            maskR[r] = (row < K_) ? mask_attend[site * K_ + row] * (1.0f / 30.0f) : 0.0f;
        }
        const int nmo = wv ? NM1_OFF : NM0_OFF;
        for (int ct = 0; ct < 8; ++ct) {
            int col = ct * 16 + l16;
            float bb = b3g[col];
            float cs = 0.0f;
            for (int r = 0; r < 4; ++r)
                cs += (acc[ct][r] + bb) * maskR[r];
            cs += __shfl_xor(cs, 16, 64);
            cs += __shfl_xor(cs, 32, 64);
            if (lane < 16) Fv[nmo + col] = cs;
        }
    }
    __syncthreads();   // sync4: both nm partials ready; buf1 fully dead

    // ---- tail: LN1 -> FFN -> LN2 -> out, col-split over 128 threads ----
    {
        int c = tid;
        float xb = hVb[c] + Fv[NM0_OFF + c] + Fv[NM1_OFF + c];
        float s = xb, q = xb * xb;
        for (int o = 32; o; o >>= 1) { s += __shfl_xor(s, o, 64); q += __shfl_xor(q, o, 64); }
        if (lane == 0) { Fv[LNP_OFF + wv * 2] = s; Fv[LNP_OFF + wv * 2 + 1] = q; }
        __syncthreads();   // sync5
        float sT = Fv[LNP_OFF + 0] + Fv[LNP_OFF + 2];
        float qT = Fv[LNP_OFF + 1] + Fv[LNP_OFF + 3];
        float m = sT * (1.0f / 128.0f);
        float inv = 1.0f / sqrtf(qT * (1.0f / 128.0f) - m * m + 1e-5f);
        float h = (xb - m) * inv * g1[c] + be1[c];
        Fv[HARR_OFF + c] = h;
        __syncthreads();   // sync6: h complete before cross-wave FFN1 reads

        // FFN1: 4 outputs per thread, coalesced WiF [c8][o][8]
        for (int j = 0; j < 4; ++j) {
            int o = tid + 128 * j;
            float sa = big[o], sb = 0.0f;
            for (int c8 = 0; c8 < 16; c8 += 2) {
                ushort8 v0 = *(const ushort8*)(WiF + c8 * 4096 + o * 8);
                ushort8 v1 = *(const ushort8*)(WiF + (c8 + 1) * 4096 + o * 8);
                sa += dot8(&Fv[HARR_OFF + c8 * 8], v0);
                sb += dot8(&Fv[HARR_OFF + c8 * 8 + 8], v1);
            }
            Fv[GARR_OFF + o] = gelu_f(sa + sb);
        }
        __syncthreads();   // sync7: g complete before cross-wave FFN2 reads

        // FFN2: 1 output per thread, coalesced WoF [o8][c][8]
        float d0 = bog[c], d1 = 0.0f;
        for (int o8 = 0; o8 < 64; o8 += 2) {
            ushort8 v0  = *(const ushort8*)(WoF + o8 * 1024 + c * 8);
            ushort8 v0n = *(const ushort8*)(WoF + (o8 + 1) * 1024 + c * 8);
            const float* gp = &Fv[GARR_OFF + o8 * 8];
            d0 += dot8(gp, v0);
            d1 += dot8(gp + 8, v0n);
        }
        float y = h + d0 + d1;
        float s2 = y, q2 = y * y;
        for (int o = 32; o; o >>= 1) { s2 += __shfl_xor(s2, o, 64); q2 += __shfl_xor(q2, o, 64); }
        if (lane == 0) { Fv[LNP_OFF + 4 + wv * 2] = s2; Fv[LNP_OFF + 4 + wv * 2 + 1] = q2; }
        __syncthreads();   // sync8
        float sT2 = Fv[LNP_OFF + 4] + Fv[LNP_OFF + 6];
        float qT2 = Fv[LNP_OFF + 5] + Fv[LNP_OFF + 7];
        float m2 = sT2 * (1.0f / 128.0f);
        float inv2 = 1.0f / sqrtf(qT2 * (1.0f / 128.0f) - m2 * m2 + 1e-5f);
        float mv = mask_V[site];
        out[site * 128 + c] = ((y - m2) * inv2 * g2[c] + be2[c]) * mv;
    }
}

extern "C" void kernel_launch(void* const* d_in, const int* in_sizes, int n_in,
                              void* d_out, int out_size, void* d_ws, size_t ws_size,
                              hipStream_t stream) {
    const float* h_V = (const float*)d_in[0];
    const float* h_E = (const float*)d_in[1];
    // d_in[2] = E_idx (int32, unused by reference)
    const float* Xn  = (const float*)d_in[3];
    const float* mV  = (const float*)d_in[4];
    const float* mA  = (const float*)d_in[5];
    const float* Wp  = (const float*)d_in[6];
    const float* bp  = (const float*)d_in[7];
    const float* W1  = (const float*)d_in[8];
    const float* b1  = (const float*)d_in[9];
    const float* W2  = (const float*)d_in[10];
    const float* b2  = (const float*)d_in[11];
    const float* W3  = (const float*)d_in[12];
    const float* b3  = (const float*)d_in[13];
    const float* Wi  = (const float*)d_in[14];
    const float* bi  = (const float*)d_in[15];
    const float* Wo  = (const float*)d_in[16];
    const float* bo  = (const float*)d_in[17];
    const float* g1  = (const float*)d_in[18];
    const float* be1 = (const float*)d_in[19];
    const float* g2  = (const float*)d_in[20];
    const float* be2 = (const float*)d_in[21];
    unsigned short* ws = (unsigned short*)d_ws;
    float* out = (float*)d_out;

    prep_kernel<<<960, 256, 0, stream>>>(W1, W2, W3, Wi, Wo, Wp, ws);
    main_kernel<<<B_ * L_, 128, 0, stream>>>(h_V, h_E, Xn, mV, mA, bp,
                                             b1, b2, b3, bi, bo,
                                             g1, be1, g2, be2, ws, out);
}